// Round 9
// baseline (1252.062 us; speedup 1.0000x reference)
//
#include <hip/hip_runtime.h>
#include <hip/hip_fp16.h>

#define BB 2048
#define NN 1568
#define CD 48
#define G  8                      // batches per block = waves per block
#define WSLOTS 98304              // Wh uint4 slots (1.5 MB)
#define SFLTS (BB * CD)           // floats per s accumulator buffer

typedef _Float16 h2v __attribute__((ext_vector_type(2)));

// ---- scalar-safe half2 helpers
__device__ __forceinline__ unsigned packh2(float a, float b) {
    __half2 h = __floats2half2_rn(a, b);
    unsigned r; __builtin_memcpy(&r, &h, 4); return r;
}
__device__ __forceinline__ float2 uph2(unsigned v) {
    __half2 h; __builtin_memcpy(&h, &v, 4); return __half22float2(h);
}
__device__ __forceinline__ float fdot2u(unsigned a, unsigned b, float c) {
#if __has_builtin(__builtin_amdgcn_fdot2)
    h2v av, bv;
    __builtin_memcpy(&av, &a, 4); __builtin_memcpy(&bv, &b, 4);
    return __builtin_amdgcn_fdot2(av, bv, c, false);
#else
    const float2 fa = uph2(a), fb = uph2(b);
    return c + fa.x * fb.x + fa.y * fb.y;
#endif
}
__device__ __forceinline__ unsigned hadd2u(unsigned a, unsigned b) {
    __half2 ha, hb; __builtin_memcpy(&ha, &a, 4); __builtin_memcpy(&hb, &b, 4);
    __half2 r = __hadd2(ha, hb);
    unsigned q; __builtin_memcpy(&q, &r, 4); return q;
}
__device__ __forceinline__ unsigned hfma2u(unsigned a, unsigned b, unsigned c) {
    __half2 ha, hb, hc;
    __builtin_memcpy(&ha, &a, 4); __builtin_memcpy(&hb, &b, 4); __builtin_memcpy(&hc, &c, 4);
    __half2 r = __hfma2(ha, hb, hc);
    unsigned q; __builtin_memcpy(&q, &r, 4); return q;
}

// =================== K0: W fp32 -> fp16 swizzled, + zero s1..s3 ===================
__global__ __launch_bounds__(256)
void wcast(const float* __restrict__ W, uint4* __restrict__ Wh)
{
    const int id = blockIdx.x * 256 + threadIdx.x;   // 0..24575
    float* sz = (float*)(Wh + WSLOTS);
#pragma unroll
    for (int k = 0; k < 12; ++k) sz[id + k * 24576] = 0.f;

    const int ts = id & 511;
    const int r  = id >> 9;        // 0..47
    const int dq = r & 3;
    const int ci = r >> 2;         // c*4+g
    const int g  = ci & 3;
    const int c  = ci >> 2;
    const int n  = g * 512 + ts;
    uint4* dst = Wh + (size_t)ci * 8192 + dq * 4 * 512 + ts;
    if (n < NN) {
        const float* src = W + ((size_t)(c * NN + n)) * 128 + dq * 32;
#pragma unroll
        for (int dd = 0; dd < 4; ++dd) {
            const float4 f0 = *(const float4*)(src + dd * 8);
            const float4 f1 = *(const float4*)(src + dd * 8 + 4);
            uint4 q;
            q.x = packh2(f0.x, f0.y); q.y = packh2(f0.z, f0.w);
            q.z = packh2(f1.x, f1.y); q.w = packh2(f1.z, f1.w);
            dst[dd * 512] = q;
        }
    } else {
        const uint4 z = make_uint4(0u, 0u, 0u, 0u);
#pragma unroll
        for (int dd = 0; dd < 4; ++dd) dst[dd * 512] = z;
    }
}

// =================== rpass<P>: streaming routing pass, T14 async-staged W ===================
// Block = 512 thr = 8 waves; wave w owns batch bg*8+w (8 batches share one
// LDS-staged W tile). T14 split-staging: tile r+1's 6 global loads (and the
// next row's x) are ISSUED before computing tile r, and ds_written after the
// post-compute barrier — L2 latency hides under the ~4600-cyc compute phase
// instead of serializing with it (r8: stage+drain exposed every iter, 134 us
// vs ~55 us overlapped floor).
template<int P>
__global__ __launch_bounds__(512, 1)
void rpass(const float* __restrict__ x, const uint4* __restrict__ Wh,
           const float* __restrict__ s1in, const float* __restrict__ s2in,
           float* __restrict__ sout)
{
    __shared__ uint4 wtile[3072];        // 48 KB: [s = c*16+d][ts0 0..63]
    __shared__ unsigned wv2s[G][24];
    const int t    = threadIdx.x;
    const int w    = t >> 6;
    const int lane = t & 63;
    const int chunk = blockIdx.x / (BB / G);     // 0..2 (n-chunk of 512)
    const int bg    = blockIdx.x % (BB / G);
    const int b     = bg * G + w;

    unsigned wvr[24];
    if (P > 0) {
        if (t < G * CD) {
            const int bl = t / CD, cd = t % CD;
            float v;
            {
                const float a = s1in[(size_t)(bg * G + bl) * CD + cd] * (1.0f / 3.0f);
                float q = a * a;
                q += __shfl_xor(q, 1); q += __shfl_xor(q, 2);
                q += __shfl_xor(q, 4); q += __shfl_xor(q, 8);
                v = a * sqrtf(q) / (1.f + q);                  // v1
            }
            if (P == 2) {
                const float a = s2in[(size_t)(bg * G + bl) * CD + cd];
                float q = a * a;
                q += __shfl_xor(q, 1); q += __shfl_xor(q, 2);
                q += __shfl_xor(q, 4); q += __shfl_xor(q, 8);
                v += a * sqrtf(q) / (1.f + q);                 // + v2
            }
            const float vn = __shfl_xor(v, 1);
            if ((cd & 1) == 0) wv2s[bl][cd >> 1] = packh2(v, vn);
        }
        __syncthreads();
#pragma unroll
        for (int j = 0; j < 24; ++j) wvr[j] = wv2s[w][j];
    }

    unsigned acc[24];
#pragma unroll
    for (int j = 0; j < 24; ++j) acc[j] = 0u;

    const float* xb = x + (size_t)b * NN * 8;

    // ---- staging-address bases (constant per thread) ----
    // k-th slot: q = t + k*512; stream s = q>>6; row-in-tile to = q&63.
#define GBASE(K) g##K
    int g0, g1, g2, g3, g4, g5;
    {
#define MKB(K) { const int q = t + (K) * 512; const int s = q >> 6; \
                 GBASE(K) = ((s >> 4) * 4 + chunk) * 8192 + (s & 15) * 512 + (q & 63); }
        MKB(0) MKB(1) MKB(2) MKB(3) MKB(4) MKB(5)
#undef MKB
    }
    const int nb = chunk * 512 + lane;          // row for r=0

    uint4 p0, p1, p2, p3, p4, p5;
    float4 xpa, xpc;
#define ISSUE_W(R) { p0 = Wh[g0 + (R) * 64]; p1 = Wh[g1 + (R) * 64]; \
                     p2 = Wh[g2 + (R) * 64]; p3 = Wh[g3 + (R) * 64]; \
                     p4 = Wh[g4 + (R) * 64]; p5 = Wh[g5 + (R) * 64]; }
#define ISSUE_X(R) { const float* xp_ = xb + (size_t)(nb + (R) * 64) * 8; \
                     xpa = *(const float4*)xp_; xpc = *(const float4*)(xp_ + 4); }
#define WRITE_W()  { wtile[t] = p0; wtile[t + 512] = p1; wtile[t + 1024] = p2; \
                     wtile[t + 1536] = p3; wtile[t + 2048] = p4; wtile[t + 2560] = p5; }

    // prologue: stage tile 0, load x(0)
    ISSUE_W(0) ISSUE_X(0)
    WRITE_W()
    __syncthreads();

    // ---- per-class inner: W from LDS tile / global (tail) ----
#define DO_CL(C3, LL) { \
    _Pragma("unroll") \
    for (int dq = 0; dq < 4; ++dq) { \
        const uint4 w0 = wtile[((C3) * 16 + dq * 4 + 0) * 64 + lane]; \
        const uint4 w1 = wtile[((C3) * 16 + dq * 4 + 1) * 64 + lane]; \
        const uint4 w2 = wtile[((C3) * 16 + dq * 4 + 2) * 64 + lane]; \
        const uint4 w3 = wtile[((C3) * 16 + dq * 4 + 3) * 64 + lane]; \
        const float f0 = fdot2u(w0.x,xh0,fdot2u(w0.y,xh1,fdot2u(w0.z,xh2,fdot2u(w0.w,xh3,0.f)))); \
        const float f1 = fdot2u(w1.x,xh0,fdot2u(w1.y,xh1,fdot2u(w1.z,xh2,fdot2u(w1.w,xh3,0.f)))); \
        const float f2 = fdot2u(w2.x,xh0,fdot2u(w2.y,xh1,fdot2u(w2.z,xh2,fdot2u(w2.w,xh3,0.f)))); \
        const float f3 = fdot2u(w3.x,xh0,fdot2u(w3.y,xh1,fdot2u(w3.z,xh2,fdot2u(w3.w,xh3,0.f)))); \
        const unsigned pa = packh2(f0, f1); \
        const unsigned pb = packh2(f2, f3); \
        ur[(C3) * 8 + dq * 2]     = pa; \
        ur[(C3) * 8 + dq * 2 + 1] = pb; \
        if (P > 0) { \
            LL = fdot2u(pa, wvr[(C3) * 8 + dq * 2],     LL); \
            LL = fdot2u(pb, wvr[(C3) * 8 + dq * 2 + 1], LL); \
        } \
    } }

#define DO_CG(C3, LL, GG, TS) { \
    const uint4* wp = Wh + (size_t)((C3) * 4 + (GG)) * 8192 + (TS); \
    _Pragma("unroll") \
    for (int dq = 0; dq < 4; ++dq) { \
        const uint4 w0 = wp[(dq * 4 + 0) * 512]; \
        const uint4 w1 = wp[(dq * 4 + 1) * 512]; \
        const uint4 w2 = wp[(dq * 4 + 2) * 512]; \
        const uint4 w3 = wp[(dq * 4 + 3) * 512]; \
        const float f0 = fdot2u(w0.x,xh0,fdot2u(w0.y,xh1,fdot2u(w0.z,xh2,fdot2u(w0.w,xh3,0.f)))); \
        const float f1 = fdot2u(w1.x,xh0,fdot2u(w1.y,xh1,fdot2u(w1.z,xh2,fdot2u(w1.w,xh3,0.f)))); \
        const float f2 = fdot2u(w2.x,xh0,fdot2u(w2.y,xh1,fdot2u(w2.z,xh2,fdot2u(w2.w,xh3,0.f)))); \
        const float f3 = fdot2u(w3.x,xh0,fdot2u(w3.y,xh1,fdot2u(w3.z,xh2,fdot2u(w3.w,xh3,0.f)))); \
        const unsigned pa = packh2(f0, f1); \
        const unsigned pb = packh2(f2, f3); \
        ur[(C3) * 8 + dq * 2]     = pa; \
        ur[(C3) * 8 + dq * 2 + 1] = pb; \
        if (P > 0) { \
            LL = fdot2u(pa, wvr[(C3) * 8 + dq * 2],     LL); \
            LL = fdot2u(pb, wvr[(C3) * 8 + dq * 2 + 1], LL); \
        } \
    } }

#define ROW_TAIL(BODY0, BODY1, BODY2, XA, XC) { \
    const unsigned xh0 = packh2((XA).x, (XA).y), xh1 = packh2((XA).z, (XA).w); \
    const unsigned xh2 = packh2((XC).x, (XC).y), xh3 = packh2((XC).z, (XC).w); \
    unsigned ur[24]; \
    float l0 = 0.f, l1 = 0.f, l2 = 0.f; \
    BODY0 BODY1 BODY2 \
    if (P == 0) { \
        (void)l0; (void)l1; (void)l2; \
        _Pragma("unroll") for (int j = 0; j < 24; ++j) acc[j] = hadd2u(acc[j], ur[j]); \
    } else { \
        const float e0 = __expf(l0), e1 = __expf(l1), e2 = __expf(l2); \
        const float inv = 1.f / (e0 + e1 + e2); \
        const unsigned c0h = packh2(e0 * inv, e0 * inv); \
        const unsigned c1h = packh2(e1 * inv, e1 * inv); \
        const unsigned c2h = packh2(e2 * inv, e2 * inv); \
        _Pragma("unroll") for (int j = 0; j < 8; ++j) { \
            acc[j]      = hfma2u(c0h, ur[j],      acc[j]); \
            acc[8 + j]  = hfma2u(c1h, ur[8 + j],  acc[8 + j]); \
            acc[16 + j] = hfma2u(c2h, ur[16 + j], acc[16 + j]); \
        } \
    } }

#pragma unroll 1
    for (int r = 0; r < 8; ++r) {
        const float4 xa = xpa, xc = xpc;     // current row's x (prefetched)
        if (r < 7) { ISSUE_W(r + 1) ISSUE_X(r + 1) }   // issue-early (T14)
        ROW_TAIL(DO_CL(0, l0), DO_CL(1, l1), DO_CL(2, l2), xa, xc)
        if (r < 7) {
            __syncthreads();                 // all waves done reading tile r
            WRITE_W()                        // write-late: tile r+1 -> LDS
            __syncthreads();                 // tile r+1 visible to all
        }
    }
    if (chunk == 2 && lane < 32) {           // tail rows 1536..1567 (g=3), direct global
        const int n = 1536 + lane;
        const float4 xa = *(const float4*)(xb + (size_t)n * 8);
        const float4 xc = *(const float4*)(xb + (size_t)n * 8 + 4);
        ROW_TAIL(DO_CG(0, l0, 3, lane), DO_CG(1, l1, 3, lane), DO_CG(2, l2, 3, lane), xa, xc)
    }
#undef ROW_TAIL
#undef DO_CG
#undef DO_CL
#undef ISSUE_W
#undef ISSUE_X
#undef WRITE_W
#undef GBASE

    // wave-local reduce (wave == batch), one atomic per element
    float myv = 0.f;
#pragma unroll
    for (int j = 0; j < 24; ++j) {
        float2 g_ = uph2(acc[j]);
        g_.x += __shfl_xor(g_.x, 1);  g_.y += __shfl_xor(g_.y, 1);
        g_.x += __shfl_xor(g_.x, 2);  g_.y += __shfl_xor(g_.y, 2);
        g_.x += __shfl_xor(g_.x, 4);  g_.y += __shfl_xor(g_.y, 4);
        g_.x += __shfl_xor(g_.x, 8);  g_.y += __shfl_xor(g_.y, 8);
        g_.x += __shfl_xor(g_.x, 16); g_.y += __shfl_xor(g_.y, 16);
        g_.x += __shfl_xor(g_.x, 32); g_.y += __shfl_xor(g_.y, 32);
        if ((lane >> 1) == j) myv = (lane & 1) ? g_.y : g_.x;
    }
    if (lane < CD) atomicAdd(&sout[(size_t)b * CD + lane], myv);
}

// =================== F: out = squash(s3) ===================
__global__ __launch_bounds__(256)
void fsquash(const float* __restrict__ s3, float* __restrict__ out)
{
    const int idx = blockIdx.x * 256 + threadIdx.x;    // 0..98303
    const float s = s3[idx];
    float q = s * s;
    q += __shfl_xor(q, 1); q += __shfl_xor(q, 2);
    q += __shfl_xor(q, 4); q += __shfl_xor(q, 8);
    out[idx] = s * sqrtf(q) / (1.f + q);
}

extern "C" void kernel_launch(void* const* d_in, const int* in_sizes, int n_in,
                              void* d_out, int out_size, void* d_ws, size_t ws_size,
                              hipStream_t stream) {
    (void)in_sizes; (void)n_in; (void)out_size;
    const float* x = (const float*)d_in[0];   // (B, N, 8) fp32
    const float* W = (const float*)d_in[1];   // (1, 3, N, 16, 8) fp32
    if (ws_size < (size_t)WSLOTS * 16 + (size_t)3 * SFLTS * 4) return;
    uint4* Wh = (uint4*)d_ws;
    float* s1 = (float*)d_ws + (size_t)WSLOTS * 4;
    float* s2 = s1 + SFLTS;
    float* s3 = s2 + SFLTS;

    hipLaunchKernelGGL(wcast,    dim3(96),           dim3(256), 0, stream, W, Wh);
    hipLaunchKernelGGL(rpass<0>, dim3(3 * (BB / G)), dim3(512), 0, stream, x, Wh, s1, s2, s1);
    hipLaunchKernelGGL(rpass<1>, dim3(3 * (BB / G)), dim3(512), 0, stream, x, Wh, s1, s2, s2);
    hipLaunchKernelGGL(rpass<2>, dim3(3 * (BB / G)), dim3(512), 0, stream, x, Wh, s1, s2, s3);
    hipLaunchKernelGGL(fsquash,  dim3(384),          dim3(256), 0, stream, s3, (float*)d_out);
}